// Round 6
// baseline (452.757 us; speedup 1.0000x reference)
//
#include <hip/hip_runtime.h>
#include <hip/hip_fp16.h>

// CommNet critic forward. R6: R5 structure (1 WG = 1 wave = 1 batch, M=32,
// zero cross-wave barriers) + explicit 2-group register double-buffer on the
// B-fragment stream (8-12 loads in flight -> hides ~300cyc L2 latency), and
// launch_bounds(64,1): LDS caps at 4 WGs/CU anyway, so use the full reg file.

#define NB   2048
#define NA   32
#define DIN  128
#define HID  256
#define SA   264   // f16 row stride: l16*132 words -> 2-way bank alias (free)

typedef _Float16 half8   __attribute__((ext_vector_type(8)));
typedef _Float16 half4_t __attribute__((ext_vector_type(4)));
typedef float    float4v __attribute__((ext_vector_type(4)));

// f16 weight-fragment arena in d_ws (element offsets)
#define ENC_OFF    0
#define FOBS_OFF   32768
#define WIH_OFF    98304
#define WHH_OFF    294912
#define PREP_TOTAL 491520   // f16 elements -> 983040 bytes

// One wave per (matrix, ks, nt) fragment tile; coalesced f32x4 reads, half8 write.
// frag[((ks*NT + nt)*64 + lane)*8 + j] = W[nt*16 + lane%16][ks*32 + (lane/16)*8 + j]
__global__ __launch_bounds__(256) void prep_weights(
        const float* __restrict__ encW, const float* __restrict__ fobsW,
        const float* __restrict__ wih,  const float* __restrict__ whh,
        _Float16* __restrict__ prep) {
    int W = blockIdx.x * 4 + (threadIdx.x >> 6);   // wave id 0..959
    int lane = threadIdx.x & 63;
    const float* src; int K, NT, base, idx;
    if (W < 64)       { src = encW;  K = 128; NT = 16; base = ENC_OFF;  idx = W; }
    else if (W < 192) { src = fobsW; K = 256; NT = 16; base = FOBS_OFF; idx = W - 64; }
    else if (W < 576) { src = wih;   K = 256; NT = 48; base = WIH_OFF;  idx = W - 192; }
    else              { src = whh;   K = 256; NT = 48; base = WHH_OFF;  idx = W - 576; }
    int nt = idx % NT, ks = idx / NT;
    int l16 = lane & 15, q = lane >> 4;
    const float* s = src + (size_t)(nt * 16 + l16) * K + ks * 32 + q * 8;
    float4v f0 = *(const float4v*)s;
    float4v f1 = *(const float4v*)(s + 4);
    half8 h;
    h[0] = (_Float16)f0[0]; h[1] = (_Float16)f0[1]; h[2] = (_Float16)f0[2]; h[3] = (_Float16)f0[3];
    h[4] = (_Float16)f1[0]; h[5] = (_Float16)f1[1]; h[6] = (_Float16)f1[2]; h[7] = (_Float16)f1[3];
    *(half8*)(prep + base + (((size_t)(ks * NT + nt) * 64 + lane) << 3)) = h;
}

__device__ __forceinline__ float sigmoid_f(float x) {
    x = fminf(fmaxf(x, -30.f), 30.f);
    return 1.f / (1.f + __expf(-x));
}
__device__ __forceinline__ float tanh_f(float x) {
    x = fminf(fmaxf(x, -15.f), 15.f);
    float e = __expf(-2.f * x);
    return (1.f - e) / (1.f + e);
}
__device__ __forceinline__ void zero24(float4v a[2][4]) {
    float4v z = {0.f, 0.f, 0.f, 0.f};
    #pragma unroll
    for (int m = 0; m < 2; m++)
        #pragma unroll
        for (int n = 0; n < 4; n++) a[m][n] = z;
}

// One wave: 32 rows (2 m-tiles) x 64 cols (4 ntiles), software-pipelined:
// B groups double-buffered in registers, group ks+2 issued before MFMA of ks.
// Steady state: 8 outstanding b128 loads -> s_waitcnt vmcnt(8), never 0.
template<int KSTEPS, int USE_PREP>
__device__ __forceinline__ void gemm2x4(
        const _Float16* __restrict__ Ab,
        const _Float16* __restrict__ Bp, int ldbk,
        const float* __restrict__ rawp, int K,
        float4v acc[2][4])
{
    half8 bA[4], bB[4];
    #pragma unroll
    for (int nn = 0; nn < 4; nn++) {
        if (USE_PREP) bA[nn] = *(const half8*)(Bp + nn * 512);
        else {
            #pragma unroll
            for (int j = 0; j < 8; j++)
                bA[nn][j] = (_Float16)rawp[(size_t)nn * 16 * K + j];
        }
    }
    if (KSTEPS > 1) {
        #pragma unroll
        for (int nn = 0; nn < 4; nn++) {
            if (USE_PREP) bB[nn] = *(const half8*)(Bp + ldbk + nn * 512);
            else {
                #pragma unroll
                for (int j = 0; j < 8; j++)
                    bB[nn][j] = (_Float16)rawp[(size_t)nn * 16 * K + 32 + j];
            }
        }
    }
    #pragma unroll
    for (int ks = 0; ks < KSTEPS; ks++) {
        half8 a0 = *(const half8*)(Ab + ks * 32);
        half8 a1 = *(const half8*)(Ab + 16 * SA + ks * 32);
        half8 cur[4];
        #pragma unroll
        for (int nn = 0; nn < 4; nn++) cur[nn] = bA[nn];
        #pragma unroll
        for (int nn = 0; nn < 4; nn++) bA[nn] = bB[nn];
        if (ks + 2 < KSTEPS) {
            #pragma unroll
            for (int nn = 0; nn < 4; nn++) {
                if (USE_PREP) bB[nn] = *(const half8*)(Bp + (ks + 2) * ldbk + nn * 512);
                else {
                    #pragma unroll
                    for (int j = 0; j < 8; j++)
                        bB[nn][j] = (_Float16)rawp[(size_t)nn * 16 * K + (ks + 2) * 32 + j];
                }
            }
        }
        #pragma unroll
        for (int nn = 0; nn < 4; nn++) {
            acc[0][nn] = __builtin_amdgcn_mfma_f32_16x16x32_f16(a0, cur[nn], acc[0][nn], 0, 0, 0);
            acc[1][nn] = __builtin_amdgcn_mfma_f32_16x16x32_f16(a1, cur[nn], acc[1][nn], 0, 0, 0);
        }
    }
}

template<int USE_PREP>
__global__ __launch_bounds__(64, 1) void commnet_fused(
    const float* __restrict__ obs, const _Float16* __restrict__ prep,
    const float* __restrict__ enc_b, const float* __restrict__ fobs_b,
    const float* __restrict__ b_ih, const float* __restrict__ b_hh,
    const float* __restrict__ dec_W, const float* __restrict__ dec_b,
    float* __restrict__ out,
    const float* __restrict__ encW, const float* __restrict__ fobsW,
    const float* __restrict__ wih, const float* __restrict__ whh)
{
    const int b     = blockIdx.x;
    const int lane  = threadIdx.x;       // 0..63, one wave per WG
    const int l16   = lane & 15;
    const int quad  = lane >> 4;
    const int kq    = quad << 3;
    const int lane8 = lane << 3;

    __shared__ __align__(16) _Float16 buf[2][NA * SA];  // ping-pong activation tiles
    __shared__ __align__(16) float Sarr[HID];           // colsums for comm

    _Float16* b0 = &buf[0][0];
    _Float16* b1 = &buf[1][0];
    const _Float16* Ab0 = b0 + l16 * SA + kq;
    const _Float16* Ab1 = b1 + l16 * SA + kq;

    // ---- stage obs 32x128 (fp32 -> f16 LDS b0)
    {
        const float* obsb = obs + (size_t)b * NA * DIN;
        #pragma unroll
        for (int it = 0; it < 16; it++) {
            int i = it * 64 + lane;           // float4 idx, 1024 total
            float4v v = ((const float4v*)obsb)[i];
            int row = i >> 5, c4 = (i & 31) * 4;
            half4_t hv;
            hv[0] = (_Float16)v[0]; hv[1] = (_Float16)v[1];
            hv[2] = (_Float16)v[2]; hv[3] = (_Float16)v[3];
            *(half4_t*)(b0 + row * SA + c4) = hv;
        }
    }
    __syncthreads();   // single-wave WG: cheap LDS fence

    float4v acc[2][4];

    // ---- encoder: e = relu(obs @ encW^T + b) : b0 -> b1   (K=128, NT=16)
    #pragma unroll 1
    for (int ch = 0; ch < 4; ch++) {
        zero24(acc);
        gemm2x4<4, USE_PREP>(Ab0, prep + ENC_OFF + (ch * 4) * 512 + lane8, 16 * 512,
                             encW + (size_t)((ch * 4) * 16 + l16) * DIN + kq, DIN, acc);
        #pragma unroll
        for (int nn = 0; nn < 4; nn++) {
            int col = ch * 64 + nn * 16 + l16;
            float bb = enc_b[col];
            #pragma unroll
            for (int mt = 0; mt < 2; mt++)
                #pragma unroll
                for (int rr = 0; rr < 4; rr++)
                    b1[(mt * 16 + quad * 4 + rr) * SA + col] =
                        (_Float16)fmaxf(acc[mt][nn][rr] + bb, 0.f);
        }
    }
    __syncthreads();

    // ---- fobs: h = e @ fobsW^T + b : b1 -> b0   (K=256, NT=16)
    #pragma unroll 1
    for (int ch = 0; ch < 4; ch++) {
        zero24(acc);
        gemm2x4<8, USE_PREP>(Ab1, prep + FOBS_OFF + (ch * 4) * 512 + lane8, 16 * 512,
                             fobsW + (size_t)((ch * 4) * 16 + l16) * HID + kq, HID, acc);
        #pragma unroll
        for (int nn = 0; nn < 4; nn++) {
            int col = ch * 64 + nn * 16 + l16;
            float bb = fobs_b[col];
            #pragma unroll
            for (int mt = 0; mt < 2; mt++)
                #pragma unroll
                for (int rr = 0; rr < 4; rr++)
                    b0[(mt * 16 + quad * 4 + rr) * SA + col] =
                        (_Float16)(acc[mt][nn][rr] + bb);
        }
    }
    __syncthreads();

    // ---- GRU1 (x=0 => gi = b_ih). A = b0 (h). h1 -> b1; colsums -> Sarr
    #pragma unroll 1
    for (int ch = 0; ch < 4; ch++) {
        float rg[2][4][4];
        zero24(acc);   // r-gate: nt 0..15
        gemm2x4<8, USE_PREP>(Ab0, prep + WHH_OFF + (0 + ch * 4) * 512 + lane8, 48 * 512,
                             whh + (size_t)((0 + ch * 4) * 16 + l16) * HID + kq, HID, acc);
        #pragma unroll
        for (int nn = 0; nn < 4; nn++) {
            int col = ch * 64 + nn * 16 + l16;
            float bb = b_ih[col] + b_hh[col];
            #pragma unroll
            for (int mt = 0; mt < 2; mt++)
                #pragma unroll
                for (int rr = 0; rr < 4; rr++)
                    rg[mt][nn][rr] = sigmoid_f(acc[mt][nn][rr] + bb);
        }
        zero24(acc);   // n-gate: nt 32..47
        gemm2x4<8, USE_PREP>(Ab0, prep + WHH_OFF + (32 + ch * 4) * 512 + lane8, 48 * 512,
                             whh + (size_t)((32 + ch * 4) * 16 + l16) * HID + kq, HID, acc);
        #pragma unroll
        for (int nn = 0; nn < 4; nn++) {
            int col = ch * 64 + nn * 16 + l16;
            float bi = b_ih[512 + col], bh = b_hh[512 + col];
            #pragma unroll
            for (int mt = 0; mt < 2; mt++)
                #pragma unroll
                for (int rr = 0; rr < 4; rr++)
                    rg[mt][nn][rr] = tanh_f(bi + rg[mt][nn][rr] * (acc[mt][nn][rr] + bh));
        }
        zero24(acc);   // z-gate: nt 16..31
        gemm2x4<8, USE_PREP>(Ab0, prep + WHH_OFF + (16 + ch * 4) * 512 + lane8, 48 * 512,
                             whh + (size_t)((16 + ch * 4) * 16 + l16) * HID + kq, HID, acc);
        #pragma unroll
        for (int nn = 0; nn < 4; nn++) {
            int col = ch * 64 + nn * 16 + l16;
            float bb = b_ih[256 + col] + b_hh[256 + col];
            float s = 0.f;
            #pragma unroll
            for (int mt = 0; mt < 2; mt++)
                #pragma unroll
                for (int rr = 0; rr < 4; rr++) {
                    int row = mt * 16 + quad * 4 + rr;
                    float z = sigmoid_f(acc[mt][nn][rr] + bb);
                    float hold = (float)b0[row * SA + col];
                    float h1 = (1.f - z) * rg[mt][nn][rr] + z * hold;
                    b1[row * SA + col] = (_Float16)h1;
                    s += h1;
                }
            s += __shfl_xor(s, 16);        // full 32-row colsum
            s += __shfl_xor(s, 32);
            if (lane < 16) Sarr[(ch * 4 + nn) * 16 + lane] = s;
        }
    }
    __syncthreads();

    // ---- comm: c = (Sarr - h1)/32 : b1 -> b0 (h dead)
    #pragma unroll
    for (int it = 0; it < 16; it++) {
        int g = it * 64 + lane;               // half8 group, 1024 total
        int row = g >> 5, cg = (g & 31) * 8;
        half8 hv = *(const half8*)(b1 + row * SA + cg);
        float4v s0 = *(const float4v*)(&Sarr[cg]);
        float4v s1 = *(const float4v*)(&Sarr[cg + 4]);
        half8 cv;
        #pragma unroll
        for (int j = 0; j < 4; j++) {
            cv[j]     = (_Float16)((s0[j] - (float)hv[j])     * (1.f / 32.f));
            cv[4 + j] = (_Float16)((s1[j] - (float)hv[4 + j]) * (1.f / 32.f));
        }
        *(half8*)(b0 + row * SA + cg) = cv;
    }
    __syncthreads();

    // ---- GRU2: gi = c(b0) @ W_ih, gh = h1(b1) @ W_hh; fused decoder dot
    float p[2][4] = {};
    #pragma unroll 1
    for (int ch = 0; ch < 4; ch++) {
        float rg[2][4][4], tg[2][4][4];
        zero24(acc);   // r-gate: chain gi_r + gh_r
        gemm2x4<8, USE_PREP>(Ab0, prep + WIH_OFF + (0 + ch * 4) * 512 + lane8, 48 * 512,
                             wih + (size_t)((0 + ch * 4) * 16 + l16) * HID + kq, HID, acc);
        gemm2x4<8, USE_PREP>(Ab1, prep + WHH_OFF + (0 + ch * 4) * 512 + lane8, 48 * 512,
                             whh + (size_t)((0 + ch * 4) * 16 + l16) * HID + kq, HID, acc);
        #pragma unroll
        for (int nn = 0; nn < 4; nn++) {
            int col = ch * 64 + nn * 16 + l16;
            float bb = b_ih[col] + b_hh[col];
            #pragma unroll
            for (int mt = 0; mt < 2; mt++)
                #pragma unroll
                for (int rr = 0; rr < 4; rr++)
                    rg[mt][nn][rr] = sigmoid_f(acc[mt][nn][rr] + bb);
        }
        zero24(acc);   // gh_n
        gemm2x4<8, USE_PREP>(Ab1, prep + WHH_OFF + (32 + ch * 4) * 512 + lane8, 48 * 512,
                             whh + (size_t)((32 + ch * 4) * 16 + l16) * HID + kq, HID, acc);
        #pragma unroll
        for (int nn = 0; nn < 4; nn++) {
            int col = ch * 64 + nn * 16 + l16;
            float bh = b_hh[512 + col];
            #pragma unroll
            for (int mt = 0; mt < 2; mt++)
                #pragma unroll
                for (int rr = 0; rr < 4; rr++)
                    tg[mt][nn][rr] = acc[mt][nn][rr] + bh;
        }
        zero24(acc);   // gi_n
        gemm2x4<8, USE_PREP>(Ab0, prep + WIH_OFF + (32 + ch * 4) * 512 + lane8, 48 * 512,
                             wih + (size_t)((32 + ch * 4) * 16 + l16) * HID + kq, HID, acc);
        #pragma unroll
        for (int nn = 0; nn < 4; nn++) {
            int col = ch * 64 + nn * 16 + l16;
            float bi = b_ih[512 + col];
            #pragma unroll
            for (int mt = 0; mt < 2; mt++)
                #pragma unroll
                for (int rr = 0; rr < 4; rr++)
                    rg[mt][nn][rr] = tanh_f(acc[mt][nn][rr] + bi
                                            + rg[mt][nn][rr] * tg[mt][nn][rr]);
        }
        zero24(acc);   // z-gate: chain gi_z + gh_z
        gemm2x4<8, USE_PREP>(Ab0, prep + WIH_OFF + (16 + ch * 4) * 512 + lane8, 48 * 512,
                             wih + (size_t)((16 + ch * 4) * 16 + l16) * HID + kq, HID, acc);
        gemm2x4<8, USE_PREP>(Ab1, prep + WHH_OFF + (16 + ch * 4) * 512 + lane8, 48 * 512,
                             whh + (size_t)((16 + ch * 4) * 16 + l16) * HID + kq, HID, acc);
        #pragma unroll
        for (int nn = 0; nn < 4; nn++) {
            int col = ch * 64 + nn * 16 + l16;
            float bb = b_ih[256 + col] + b_hh[256 + col];
            float dwv = dec_W[col];
            #pragma unroll
            for (int mt = 0; mt < 2; mt++)
                #pragma unroll
                for (int rr = 0; rr < 4; rr++) {
                    int row = mt * 16 + quad * 4 + rr;
                    float z = sigmoid_f(acc[mt][nn][rr] + bb);
                    float h1v = (float)b1[row * SA + col];
                    float h2 = (1.f - z) * rg[mt][nn][rr] + z * h1v;
                    p[mt][rr] += h2 * dwv;
                }
        }
    }

    // ---- decoder reduce over cols (l16) and store 32 rows
    #pragma unroll
    for (int m = 1; m <= 8; m <<= 1)
        #pragma unroll
        for (int mt = 0; mt < 2; mt++)
            #pragma unroll
            for (int rr = 0; rr < 4; rr++)
                p[mt][rr] += __shfl_xor(p[mt][rr], m);
    if (l16 == 0) {
        float db = dec_b[0];
        #pragma unroll
        for (int mt = 0; mt < 2; mt++)
            #pragma unroll
            for (int rr = 0; rr < 4; rr++)
                out[(size_t)b * NA + mt * 16 + quad * 4 + rr] = p[mt][rr] + db;
    }
}

extern "C" void kernel_launch(void* const* d_in, const int* in_sizes, int n_in,
                              void* d_out, int out_size, void* d_ws, size_t ws_size,
                              hipStream_t stream) {
    const float* obs   = (const float*)d_in[0];
    // d_in[1] (act) unused by reference
    const float* encW  = (const float*)d_in[2];
    const float* encb  = (const float*)d_in[3];
    const float* fobsW = (const float*)d_in[4];
    const float* fobsb = (const float*)d_in[5];
    const float* wih   = (const float*)d_in[6];
    const float* bih   = (const float*)d_in[7];
    const float* whh   = (const float*)d_in[8];
    const float* bhh   = (const float*)d_in[9];
    const float* decW  = (const float*)d_in[10];
    const float* decb  = (const float*)d_in[11];
    float* out = (float*)d_out;

    _Float16* prep = (_Float16*)d_ws;
    if (ws_size >= (size_t)PREP_TOTAL * sizeof(_Float16)) {
        prep_weights<<<240, 256, 0, stream>>>(encW, fobsW, wih, whh, prep);
        commnet_fused<1><<<NB, 64, 0, stream>>>(obs, prep, encb, fobsb, bih, bhh,
                                                decW, decb, out, encW, fobsW, wih, whh);
    } else {
        commnet_fused<0><<<NB, 64, 0, stream>>>(obs, prep, encb, fobsb, bih, bhh,
                                                decW, decb, out, encW, fobsW, wih, whh);
    }
}